// Round 1
// 778.102 us; speedup vs baseline: 1.1518x; 1.1518x over previous
//
#include <hip/hip_runtime.h>
#include <hip/hip_bf16.h>

typedef __bf16 bf16_t;
typedef __bf16 bf16x8 __attribute__((ext_vector_type(8)));
typedef float f32x4 __attribute__((ext_vector_type(4)));

#define B_  4
#define S_  2048
#define H_  16
#define DK_ 128
#define DM_ 2048
#define BS_ (B_ * S_)          // 8192 rows

static __device__ __forceinline__ f32x4 mfma16(bf16x8 a, bf16x8 b, f32x4 c) {
  return __builtin_amdgcn_mfma_f32_16x16x32_bf16(a, b, c, 0, 0, 0);
}

// async global->LDS 16B copy. lds base must be wave-uniform; HW scatters lane*16.
static __device__ __forceinline__ void async_copy16(const bf16_t* g, bf16_t* l) {
  __builtin_amdgcn_global_load_lds(
      (const __attribute__((address_space(1))) void*)g,
      (__attribute__((address_space(3))) void*)l, 16, 0, 0);
}

// ---------------------------------------------------------------------------
// fp32 -> bf16 elementwise convert (8 elems/thread)
// ---------------------------------------------------------------------------
__global__ __launch_bounds__(256) void cvt_bf16(const float* __restrict__ in,
                                                bf16_t* __restrict__ out, int n8) {
  int i = blockIdx.x * 256 + threadIdx.x;
  if (i < n8) {
    const float4* p = (const float4*)in + (size_t)i * 2;
    float4 f0 = p[0], f1 = p[1];
    bf16x8 r;
    r[0] = (bf16_t)f0.x; r[1] = (bf16_t)f0.y; r[2] = (bf16_t)f0.z; r[3] = (bf16_t)f0.w;
    r[4] = (bf16_t)f1.x; r[5] = (bf16_t)f1.y; r[6] = (bf16_t)f1.z; r[7] = (bf16_t)f1.w;
    ((bf16x8*)out)[i] = r;
  }
}

// ---------------------------------------------------------------------------
// C[M,N] = A[M,K] * B[N,K]^T, bf16 in, fp32 acc, TC out. m97-style staging:
// global_load_lds dwordx4 into unpadded 128x32 LDS tiles. 128x128 block tile,
// 4 waves 2x2, each wave 64x64 via 4x4 of 16x16x32 MFMAs. BK=32.
// VTOUT: write C per-head-transposed into Vt layout [(b*16+h)*128+d][s].
// ---------------------------------------------------------------------------
template <typename TC, bool VTOUT>
__global__ __launch_bounds__(256) void gemm_bt(const bf16_t* __restrict__ A,
                                               const bf16_t* __restrict__ B,
                                               TC* __restrict__ C,
                                               int M, int N, int K) {
  __shared__ bf16_t As[128 * 32];
  __shared__ bf16_t Bs[128 * 32];

  const int tid  = threadIdx.x;
  const int wave = tid >> 6;
  const int lane = tid & 63;
  const int quad = lane >> 4;
  const int l16  = lane & 15;
  const int wm   = (wave & 1) * 64;
  const int wn   = (wave >> 1) * 64;
  const int bm   = blockIdx.x * 128;
  const int bn   = blockIdx.y * 128;

  // chunk c covers LDS elems [c*8, c*8+8): row=c>>2, col=(c&3)*8 (stride 32).
  const int c0 = wave * 128 + lane;
  const int c1 = wave * 128 + 64 + lane;
  const int r0 = c0 >> 2, o0 = (c0 & 3) * 8;
  const int r1 = c1 >> 2, o1 = (c1 & 3) * 8;

  const bf16_t* Ar0 = A + (size_t)(bm + r0) * K + o0;
  const bf16_t* Ar1 = A + (size_t)(bm + r1) * K + o1;
  const bf16_t* Br0 = B + (size_t)(bn + r0) * K + o0;
  const bf16_t* Br1 = B + (size_t)(bn + r1) * K + o1;
  bf16_t* as0 = As + wave * 1024;      // wave-uniform LDS bases
  bf16_t* as1 = As + wave * 1024 + 512;
  bf16_t* bs0 = Bs + wave * 1024;
  bf16_t* bs1 = Bs + wave * 1024 + 512;

  f32x4 acc[4][4];
#pragma unroll
  for (int i = 0; i < 4; ++i)
#pragma unroll
    for (int j = 0; j < 4; ++j) acc[i][j] = (f32x4){0.f, 0.f, 0.f, 0.f};

  for (int k0 = 0; k0 < K; k0 += 32) {
    __syncthreads();                 // prior iteration's LDS reads done
    async_copy16(Ar0 + k0, as0);
    async_copy16(Ar1 + k0, as1);
    async_copy16(Br0 + k0, bs0);
    async_copy16(Br1 + k0, bs1);
    __syncthreads();                 // drains vmcnt -> staged data visible

    bf16x8 af[4], bfr[4];
#pragma unroll
    for (int mt = 0; mt < 4; ++mt)
      af[mt] = *(const bf16x8*)(As + (wm + mt * 16 + l16) * 32 + quad * 8);
#pragma unroll
    for (int nt = 0; nt < 4; ++nt)
      bfr[nt] = *(const bf16x8*)(Bs + (wn + nt * 16 + l16) * 32 + quad * 8);
#pragma unroll
    for (int mt = 0; mt < 4; ++mt)
#pragma unroll
      for (int nt = 0; nt < 4; ++nt)
        acc[mt][nt] = mfma16(af[mt], bfr[nt], acc[mt][nt]);
  }

#pragma unroll
  for (int mt = 0; mt < 4; ++mt)
#pragma unroll
    for (int nt = 0; nt < 4; ++nt)
#pragma unroll
      for (int v = 0; v < 4; ++v) {
        int row = bm + wm + mt * 16 + quad * 4 + v;
        int col = bn + wn + nt * 16 + l16;
        if constexpr (VTOUT) {
          // row = b*S+s, col = h*128+d -> Vt[((b*16+h)*128+d)*S + s]
          size_t o = (size_t)(((row >> 11) * 16 + (col >> 7)) * 128 + (col & 127)) * S_ +
                     (row & 2047);
          C[o] = (TC)acc[mt][nt][v];
        } else {
          C[(size_t)row * N + col] = (TC)acc[mt][nt][v];
        }
      }
}

// ---------------------------------------------------------------------------
// Flash attention, latency-hiding rewrite:
//  * K/V double-buffered in LDS, staged with global_load_lds issued one tile
//    ahead -> the single __syncthreads per tile drains vmcnt AFTER a full
//    compute phase (T3-minimum pipeline; removes the per-tile latency convoy).
//  * Unpadded tiles with XOR swizzle (elem ^= (row&7)<<3). global_load_lds
//    writes linearly, so the SOURCE addresses are inverse-swizzled and every
//    LDS read applies the same XOR (m201 both-sides rule). Kills the 1.85e7
//    bank-conflict cycles of the padded layout.
//  * XCD-aware block remap: each XCD owns 8 heads, heavy q-blocks first ->
//    ~2 concurrent heads (~2MB K+V) per 4MiB XCD L2.
//  * defer-max (THR=8, exp2 domain) skips the O-rescale on most tiles;
//    s_setprio(1) around MFMA clusters.
// LDS: Ks 2x16KB + Vs 2x16KB + QPs 16KB = 80KB -> 2 blocks/CU.
// Q,K: [b*S+s][h*128+d] bf16.  VT: [(b*16+h)*128+d][s] bf16.  O like Q.
// ---------------------------------------------------------------------------
__global__ __launch_bounds__(256, 2) void attn_kernel(const bf16_t* __restrict__ Q,
                                                      const bf16_t* __restrict__ K,
                                                      const bf16_t* __restrict__ VT,
                                                      bf16_t* __restrict__ O,
                                                      const int* __restrict__ use_mask) {
  __shared__ bf16_t Ks[2 * 64 * 128];   // [buf][k][d], XOR-swizzled
  __shared__ bf16_t Vs[2 * 128 * 64];   // [buf][d][k], XOR-swizzled
  __shared__ bf16_t QPs[64 * 128];      // Q stage (swizzled), then per-wave P

  const int tid  = threadIdx.x;
  const int wave = tid >> 6;
  const int lane = tid & 63;
  const int quad = lane >> 4;
  const int l16  = lane & 15;

  // XCD-aware remap: linear dispatch id -> (bh, qb). xcd = lid%8 (round-robin
  // placement); each xcd streams heads {xcd, xcd+8, ...}, heavy qb first.
  const int lid = (int)(blockIdx.y * gridDim.x + blockIdx.x);
  const int xcd = lid & 7;
  const int t8  = lid >> 3;                 // 0..255
  const int bh  = xcd + ((t8 >> 5) << 3);   // 8 heads per XCD
  const int qb  = 31 - (t8 & 31);           // heavy blocks first
  const int b = bh >> 4, h = bh & 15;
  const int maskflag = *use_mask;

  const size_t qk_base = ((size_t)b * S_ + (size_t)qb * 64) * DM_ + h * DK_;

  // Pre-swizzled staging source offsets: LDS chunk n holds data chunk
  // (r, q^(r&7)) so that read addr  row*W + (col ^ ((row&7)<<3))  is linear.
  int skO[4], svO[4];
#pragma unroll
  for (int p = 0; p < 4; ++p) {
    int rK = p * 16 + wave * 4 + quad;                 // K/Q row (16 chunks/row)
    skO[p] = rK * DM_ + ((l16 ^ (rK & 7)) * 8);
    int dV = p * 32 + wave * 8 + (lane >> 3);          // V row (8 chunks/row)
    svO[p] = dV * S_ + (((lane & 7) ^ (dV & 7)) * 8);
  }

  const bf16_t* Kbase = K + (size_t)b * S_ * DM_ + h * DK_;
  const bf16_t* Vbase = VT + (size_t)bh * DK_ * S_;

  auto stage_kv = [&](int j, int buf) __attribute__((always_inline)) {
    const bf16_t* kb = Kbase + (size_t)j * 64 * DM_;
    const bf16_t* vb = Vbase + (size_t)j * 64;
    bf16_t* kl = Ks + buf * 8192 + wave * 512;         // wave-uniform bases
    bf16_t* vl = Vs + buf * 8192 + wave * 512;
#pragma unroll
    for (int p = 0; p < 4; ++p) {
      async_copy16(kb + skO[p], kl + p * 2048);
      async_copy16(vb + svO[p], vl + p * 2048);
    }
  };

  // stage Q (swizzled, via pre-swizzled source) + first K/V tile
#pragma unroll
  for (int p = 0; p < 4; ++p) {
    int rQ = p * 16 + wave * 4 + quad;
    async_copy16(Q + qk_base + (size_t)rQ * DM_ + ((l16 ^ (rQ & 7)) * 8),
                 QPs + wave * 512 + p * 2048);
  }
  stage_kv(0, 0);
  __syncthreads();                       // drains all async copies

  bf16x8 qf[4];
#pragma unroll
  for (int kk = 0; kk < 4; ++kk)
    qf[kk] = *(const bf16x8*)(QPs + (wave * 16 + l16) * 128 +
                              ((kk * 32 + quad * 8) ^ ((l16 & 7) << 3)));

  f32x4 acc[8];
#pragma unroll
  for (int i = 0; i < 8; ++i) acc[i] = (f32x4){0.f, 0.f, 0.f, 0.f};
  float mrow[4], lrow[4];
#pragma unroll
  for (int v = 0; v < 4; ++v) { mrow[v] = -INFINITY; lrow[v] = 0.f; }

  // wave-private P: rows [16w,16w+16), cols [0,64) of QPs, same XOR swizzle.
  // Own wave's qf preload (in-order DS pipe) precedes any P write; other
  // waves' rows are disjoint.
  bf16_t* Pw = QPs + wave * 16 * 128;

  // softmax in exp2 domain: p = 2^(s*scale*log2e - m)
  const float c1 = 0.08838834764831845f * 1.4426950408889634f;

  const int ntiles = maskflag ? (qb + 1) : (S_ / 64);

  for (int t = 0; t < ntiles; ++t) {
    const int cur = t & 1;
    if (t + 1 < ntiles) stage_kv(t + 1, cur ^ 1);   // prefetch next tile
    const bf16_t* KsB = Ks + cur * 8192;
    const bf16_t* VsB = Vs + cur * 8192;
    const bool masked = maskflag && (t == ntiles - 1);

    // S = Q K^T : 16 queries x 64 keys
    f32x4 s[4];
#pragma unroll
    for (int nt = 0; nt < 4; ++nt) s[nt] = (f32x4){0.f, 0.f, 0.f, 0.f};
    __builtin_amdgcn_s_setprio(1);
#pragma unroll
    for (int kk = 0; kk < 4; ++kk) {
#pragma unroll
      for (int nt = 0; nt < 4; ++nt) {
        bf16x8 kf = *(const bf16x8*)(KsB + (nt * 16 + l16) * 128 +
                                     ((kk * 32 + quad * 8) ^ ((l16 & 7) << 3)));
        s[nt] = mfma16(qf[kk], kf, s[nt]);
      }
    }
    __builtin_amdgcn_s_setprio(0);

    // scale (+mask). C/D layout: row(query)=quad*4+v, col(key)=l16.
    float sv[4][4];
#pragma unroll
    for (int nt = 0; nt < 4; ++nt)
#pragma unroll
      for (int v = 0; v < 4; ++v) {
        float x = s[nt][v] * c1;
        if (masked) {
          int kg = nt * 16 + l16;
          int qg = wave * 16 + quad * 4 + v;
          if (kg > qg) x = -INFINITY;
        }
        sv[nt][v] = x;
      }

    // online softmax per query row; defer-max: skip O-rescale while the tile
    // max stays within 2^8 of the running max (first tile always rescales).
#pragma unroll
    for (int v = 0; v < 4; ++v) {
      float r = fmaxf(fmaxf(sv[0][v], sv[1][v]), fmaxf(sv[2][v], sv[3][v]));
      r = fmaxf(r, __shfl_xor(r, 1));
      r = fmaxf(r, __shfl_xor(r, 2));
      r = fmaxf(r, __shfl_xor(r, 4));
      r = fmaxf(r, __shfl_xor(r, 8));
      float m = mrow[v];
      if (r > m + 8.f) {
        float alpha = __builtin_amdgcn_exp2f(m - r);   // -inf -> 0 on tile 0
        lrow[v] *= alpha;
#pragma unroll
        for (int dt = 0; dt < 8; ++dt) acc[dt][v] *= alpha;
        mrow[v] = r;
        m = r;
      }
      float rs = 0.f;
      float pr[4];
#pragma unroll
      for (int nt = 0; nt < 4; ++nt) {
        float p = __builtin_amdgcn_exp2f(sv[nt][v] - m);
        pr[nt] = p;
        rs += p;
      }
      rs += __shfl_xor(rs, 1);
      rs += __shfl_xor(rs, 2);
      rs += __shfl_xor(rs, 4);
      rs += __shfl_xor(rs, 8);
      lrow[v] += rs;
      int prow = quad * 4 + v;
#pragma unroll
      for (int nt = 0; nt < 4; ++nt)
        Pw[prow * 128 + ((nt * 16 + l16) ^ ((prow & 7) << 3))] = (bf16_t)pr[nt];
    }

    // O += P V : 8 d-tiles, 64 keys (2 k-steps)
    __builtin_amdgcn_s_setprio(1);
#pragma unroll
    for (int kk = 0; kk < 2; ++kk) {
      bf16x8 pf = *(const bf16x8*)(Pw + l16 * 128 +
                                   ((kk * 32 + quad * 8) ^ ((l16 & 7) << 3)));
#pragma unroll
      for (int dt = 0; dt < 8; ++dt) {
        bf16x8 vf = *(const bf16x8*)(VsB + (dt * 16 + l16) * 64 +
                                     ((kk * 32 + quad * 8) ^ ((l16 & 7) << 3)));
        acc[dt] = mfma16(pf, vf, acc[dt]);
      }
    }
    __builtin_amdgcn_s_setprio(0);

    __syncthreads();   // all reads of buf done + prefetch into buf^1 drained
  }

  // epilogue: O[q][d] = acc / l
#pragma unroll
  for (int dt = 0; dt < 8; ++dt)
#pragma unroll
    for (int v = 0; v < 4; ++v) {
      int qr = wave * 16 + quad * 4 + v;
      float o = acc[dt][v] / lrow[v];
      O[qk_base + (size_t)qr * DM_ + dt * 16 + l16] = (bf16_t)o;
    }
}

// ---------------------------------------------------------------------------
extern "C" void kernel_launch(void* const* d_in, const int* in_sizes, int n_in,
                              void* d_out, int out_size, void* d_ws, size_t ws_size,
                              hipStream_t stream) {
  const float* x  = (const float*)d_in[0];
  const float* Wq = (const float*)d_in[1];
  const float* Wk = (const float*)d_in[2];
  const float* Wv = (const float*)d_in[3];
  const float* Wo = (const float*)d_in[4];
  const int* use_mask = (const int*)d_in[5];
  float* out = (float*)d_out;

  const size_t TSZ = (size_t)BS_ * DM_;   // 16,777,216 elems (32 MiB bf16)
  const size_t WSZ = (size_t)DM_ * DM_;   //  4,194,304 elems ( 8 MiB bf16)
  bf16_t* Qb  = (bf16_t*)d_ws;            // R0
  bf16_t* Kb  = Qb + TSZ;                 // R1
  bf16_t* Vt  = Kb + TSZ;                 // R2: Vt, then Wo_bf16 after attention
  bf16_t* xb  = Vt + TSZ;                 // R3: x_bf16, then Ob after projections
  bf16_t* Ob  = xb;
  bf16_t* Wob = Vt;
  // weight bf16 staging inside d_out (64 MiB fp32; fully overwritten at the end)
  bf16_t* wq = (bf16_t*)d_out;
  bf16_t* wk = wq + WSZ;
  bf16_t* wv = wk + WSZ;

  cvt_bf16<<<(int)(TSZ / 8 / 256), 256, 0, stream>>>(x,  xb, (int)(TSZ / 8));
  cvt_bf16<<<(int)(WSZ / 8 / 256), 256, 0, stream>>>(Wq, wq, (int)(WSZ / 8));
  cvt_bf16<<<(int)(WSZ / 8 / 256), 256, 0, stream>>>(Wk, wk, (int)(WSZ / 8));
  cvt_bf16<<<(int)(WSZ / 8 / 256), 256, 0, stream>>>(Wv, wv, (int)(WSZ / 8));

  dim3 gGemm(BS_ / 128, DM_ / 128);  // (64, 16)
  gemm_bt<bf16_t, false><<<gGemm, 256, 0, stream>>>(xb, wq, Qb, BS_, DM_, DM_);
  gemm_bt<bf16_t, false><<<gGemm, 256, 0, stream>>>(xb, wk, Kb, BS_, DM_, DM_);
  gemm_bt<bf16_t, true ><<<gGemm, 256, 0, stream>>>(xb, wv, Vt, BS_, DM_, DM_);

  dim3 gA(S_ / 64, B_ * H_);         // (32, 64)
  attn_kernel<<<gA, 256, 0, stream>>>(Qb, Kb, Vt, Ob, use_mask);

  cvt_bf16<<<(int)(WSZ / 8 / 256), 256, 0, stream>>>(Wo, Wob, (int)(WSZ / 8));
  gemm_bt<float, false><<<gGemm, 256, 0, stream>>>(Ob, Wob, out, BS_, DM_, DM_);
}

// Round 5
// 690.644 us; speedup vs baseline: 1.2977x; 1.1266x over previous
//
#include <hip/hip_runtime.h>
#include <hip/hip_bf16.h>

typedef __bf16 bf16_t;
typedef __bf16 bf16x8 __attribute__((ext_vector_type(8)));
typedef float f32x4 __attribute__((ext_vector_type(4)));

#define B_  4
#define S_  2048
#define H_  16
#define DK_ 128
#define DM_ 2048
#define BS_ (B_ * S_)          // 8192 rows

static __device__ __forceinline__ f32x4 mfma16(bf16x8 a, bf16x8 b, f32x4 c) {
  return __builtin_amdgcn_mfma_f32_16x16x32_bf16(a, b, c, 0, 0, 0);
}

// async global->LDS 16B copy. lds base must be wave-uniform; HW scatters lane*16.
static __device__ __forceinline__ void async_copy16(const bf16_t* g, bf16_t* l) {
  __builtin_amdgcn_global_load_lds(
      (const __attribute__((address_space(1))) void*)g,
      (__attribute__((address_space(3))) void*)l, 16, 0, 0);
}

// DPP row_ror (within 16-lane row) on f32 -- cross-lane reduce on the VALU
// pipe instead of DS-pipe ds_swizzle that __shfl_xor lowers to.
template <int CTRL>
static __device__ __forceinline__ float dpp_rorf(float x) {
  return __builtin_bit_cast(float,
      __builtin_amdgcn_update_dpp(0, __builtin_bit_cast(int, x), CTRL, 0xF, 0xF, true));
}
static __device__ __forceinline__ float rowmax16(float r) {
  r = fmaxf(r, dpp_rorf<0x121>(r));   // row_ror:1
  r = fmaxf(r, dpp_rorf<0x122>(r));   // row_ror:2
  r = fmaxf(r, dpp_rorf<0x124>(r));   // row_ror:4
  r = fmaxf(r, dpp_rorf<0x128>(r));   // row_ror:8
  return r;
}
static __device__ __forceinline__ float rowsum16(float r) {
  r += dpp_rorf<0x121>(r);
  r += dpp_rorf<0x122>(r);
  r += dpp_rorf<0x124>(r);
  r += dpp_rorf<0x128>(r);
  return r;
}

struct ChainOn  { static constexpr bool v = true;  };
struct ChainOff { static constexpr bool v = false; };

// ---------------------------------------------------------------------------
// fp32 -> bf16 elementwise convert (8 elems/thread)
// ---------------------------------------------------------------------------
__global__ __launch_bounds__(256) void cvt_bf16(const float* __restrict__ in,
                                                bf16_t* __restrict__ out, int n8) {
  int i = blockIdx.x * 256 + threadIdx.x;
  if (i < n8) {
    const float4* p = (const float4*)in + (size_t)i * 2;
    float4 f0 = p[0], f1 = p[1];
    bf16x8 r;
    r[0] = (bf16_t)f0.x; r[1] = (bf16_t)f0.y; r[2] = (bf16_t)f0.z; r[3] = (bf16_t)f0.w;
    r[4] = (bf16_t)f1.x; r[5] = (bf16_t)f1.y; r[6] = (bf16_t)f1.z; r[7] = (bf16_t)f1.w;
    ((bf16x8*)out)[i] = r;
  }
}

// ---------------------------------------------------------------------------
// C[M,N] = A[M,K] * B[N,K]^T, bf16 in, fp32 acc, TC out. m97-style staging:
// global_load_lds dwordx4 into unpadded 128x32 LDS tiles. 128x128 block tile,
// 4 waves 2x2, each wave 64x64 via 4x4 of 16x16x32 MFMAs. BK=32.
// VTOUT: write C per-head-transposed into Vt layout [(b*16+h)*128+d][s].
// ---------------------------------------------------------------------------
template <typename TC, bool VTOUT>
__global__ __launch_bounds__(256) void gemm_bt(const bf16_t* __restrict__ A,
                                               const bf16_t* __restrict__ B,
                                               TC* __restrict__ C,
                                               int M, int N, int K) {
  __shared__ bf16_t As[128 * 32];
  __shared__ bf16_t Bs[128 * 32];

  const int tid  = threadIdx.x;
  const int wave = tid >> 6;
  const int lane = tid & 63;
  const int quad = lane >> 4;
  const int l16  = lane & 15;
  const int wm   = (wave & 1) * 64;
  const int wn   = (wave >> 1) * 64;
  const int bm   = blockIdx.x * 128;
  const int bn   = blockIdx.y * 128;

  // chunk c covers LDS elems [c*8, c*8+8): row=c>>2, col=(c&3)*8 (stride 32).
  const int c0 = wave * 128 + lane;
  const int c1 = wave * 128 + 64 + lane;
  const int r0 = c0 >> 2, o0 = (c0 & 3) * 8;
  const int r1 = c1 >> 2, o1 = (c1 & 3) * 8;

  const bf16_t* Ar0 = A + (size_t)(bm + r0) * K + o0;
  const bf16_t* Ar1 = A + (size_t)(bm + r1) * K + o1;
  const bf16_t* Br0 = B + (size_t)(bn + r0) * K + o0;
  const bf16_t* Br1 = B + (size_t)(bn + r1) * K + o1;
  bf16_t* as0 = As + wave * 1024;      // wave-uniform LDS bases
  bf16_t* as1 = As + wave * 1024 + 512;
  bf16_t* bs0 = Bs + wave * 1024;
  bf16_t* bs1 = Bs + wave * 1024 + 512;

  f32x4 acc[4][4];
#pragma unroll
  for (int i = 0; i < 4; ++i)
#pragma unroll
    for (int j = 0; j < 4; ++j) acc[i][j] = (f32x4){0.f, 0.f, 0.f, 0.f};

  for (int k0 = 0; k0 < K; k0 += 32) {
    __syncthreads();                 // prior iteration's LDS reads done
    async_copy16(Ar0 + k0, as0);
    async_copy16(Ar1 + k0, as1);
    async_copy16(Br0 + k0, bs0);
    async_copy16(Br1 + k0, bs1);
    __syncthreads();                 // drains vmcnt -> staged data visible

    bf16x8 af[4], bfr[4];
#pragma unroll
    for (int mt = 0; mt < 4; ++mt)
      af[mt] = *(const bf16x8*)(As + (wm + mt * 16 + l16) * 32 + quad * 8);
#pragma unroll
    for (int nt = 0; nt < 4; ++nt)
      bfr[nt] = *(const bf16x8*)(Bs + (wn + nt * 16 + l16) * 32 + quad * 8);
#pragma unroll
    for (int mt = 0; mt < 4; ++mt)
#pragma unroll
      for (int nt = 0; nt < 4; ++nt)
        acc[mt][nt] = mfma16(af[mt], bfr[nt], acc[mt][nt]);
  }

#pragma unroll
  for (int mt = 0; mt < 4; ++mt)
#pragma unroll
    for (int nt = 0; nt < 4; ++nt)
#pragma unroll
      for (int v = 0; v < 4; ++v) {
        int row = bm + wm + mt * 16 + quad * 4 + v;
        int col = bn + wn + nt * 16 + l16;
        if constexpr (VTOUT) {
          // row = b*S+s, col = h*128+d -> Vt[((b*16+h)*128+d)*S + s]
          size_t o = (size_t)(((row >> 11) * 16 + (col >> 7)) * 128 + (col & 127)) * S_ +
                     (row & 2047);
          C[o] = (TC)acc[mt][nt][v];
        } else {
          C[(size_t)row * N + col] = (TC)acc[mt][nt][v];
        }
      }
}

// ---------------------------------------------------------------------------
// Flash attention, dual-chain load-balanced version:
//  * One workgroup owns TWO q-blocks {qa=31-p, qc=p}: constant 33 work-units
//    per block when causal (64 when not) -> no straggler tail.
//  * Both chains consume the SAME staged K/V tile: kf/vf ds_reads are shared
//    by both chains' MFMAs (DS-pipe traffic per unit of work ~halves) and the
//    two independent QK->softmax->PV chains give per-wave ILP.
//  * K/V double-buffered, global_load_lds issued one tile ahead (T3-minimum).
//  * XOR-swizzled LDS (elem ^= (row&7)<<3), inverse-swizzled global sources.
//  * Softmax reductions via DPP row_ror (VALU) instead of __shfl_xor (DS).
//  * Q direct global->reg (no LDS stage); dedicated swizzled P buffers.
//  * defer-max (THR=8, exp2 domain); s_setprio(1) around MFMA clusters.
// LDS: Ks 32K + Vs 32K + Ps 16K = 80KB -> 2 blocks/CU.
// Q,K: [b*S+s][h*128+d] bf16.  VT: [(b*16+h)*128+d][s] bf16.  O like Q.
// ---------------------------------------------------------------------------
__global__ __launch_bounds__(256, 2) void attn_kernel(const bf16_t* __restrict__ Q,
                                                      const bf16_t* __restrict__ K,
                                                      const bf16_t* __restrict__ VT,
                                                      bf16_t* __restrict__ O,
                                                      const int* __restrict__ use_mask) {
  __shared__ bf16_t Ks[2 * 64 * 128];   // [buf][k][d], XOR-swizzled
  __shared__ bf16_t Vs[2 * 128 * 64];   // [buf][d][k], XOR-swizzled
  __shared__ bf16_t Ps[2 * 4 * 16 * 64];// [chain][wave][16][64], XOR-swizzled

  const int tid  = threadIdx.x;
  const int wave = tid >> 6;
  const int lane = tid & 63;
  const int quad = lane >> 4;
  const int l16  = lane & 15;

  // XCD-aware remap over 1024 blocks: xcd = lid%8; per XCD 8 heads x 16 pairs,
  // pairs in heavy-first order.
  const int lid  = (int)(blockIdx.y * gridDim.x + blockIdx.x);
  const int xcd  = lid & 7;
  const int t8   = lid >> 3;                 // 0..127
  const int bh   = xcd + ((t8 >> 4) << 3);   // 8 heads per XCD
  const int pair = t8 & 15;
  const int qa   = 31 - pair;                // heavy q-block (17..32 tiles)
  const int qc   = pair;                     // light q-block (1..16 tiles)
  const int b = bh >> 4, h = bh & 15;
  const int maskflag = *use_mask;

  const size_t qbaseA = ((size_t)b * S_ + (size_t)qa * 64) * DM_ + h * DK_;
  const size_t qbaseC = ((size_t)b * S_ + (size_t)qc * 64) * DM_ + h * DK_;

  // Pre-swizzled staging source offsets: LDS stays linear for global_load_lds;
  // the source column is inverse-swizzled so a swizzled READ is correct.
  int skO[4], svO[4];
#pragma unroll
  for (int p = 0; p < 4; ++p) {
    int rK = p * 16 + wave * 4 + quad;                 // K row (16 chunks/row)
    skO[p] = rK * DM_ + ((l16 ^ (rK & 7)) * 8);
    int dV = p * 32 + wave * 8 + (lane >> 3);          // V row (8 chunks/row)
    svO[p] = dV * S_ + (((lane & 7) ^ (dV & 7)) * 8);
  }

  const bf16_t* Kbase = K + (size_t)b * S_ * DM_ + h * DK_;
  const bf16_t* Vbase = VT + (size_t)bh * DK_ * S_;

  auto stage_kv = [&](int j, int buf) __attribute__((always_inline)) {
    const bf16_t* kb = Kbase + (size_t)j * 64 * DM_;
    const bf16_t* vb = Vbase + (size_t)j * 64;
    bf16_t* kl = Ks + buf * 8192 + wave * 512;         // wave-uniform bases
    bf16_t* vl = Vs + buf * 8192 + wave * 512;
#pragma unroll
    for (int p = 0; p < 4; ++p) {
      async_copy16(kb + skO[p], kl + p * 2048);
      async_copy16(vb + svO[p], vl + p * 2048);
    }
  };

  // Q fragments straight from global (L2-hot, read once per block)
  bf16x8 qfA[4], qfC[4];
#pragma unroll
  for (int kk = 0; kk < 4; ++kk) {
    size_t ro = (size_t)(wave * 16 + l16) * DM_ + kk * 32 + quad * 8;
    qfA[kk] = *(const bf16x8*)(Q + qbaseA + ro);
    qfC[kk] = *(const bf16x8*)(Q + qbaseC + ro);
  }

  stage_kv(0, 0);

  f32x4 accA[8], accC[8];
#pragma unroll
  for (int i = 0; i < 8; ++i) {
    accA[i] = (f32x4){0.f, 0.f, 0.f, 0.f};
    accC[i] = (f32x4){0.f, 0.f, 0.f, 0.f};
  }
  float mA[4], lA[4], mC[4], lC[4];
#pragma unroll
  for (int v = 0; v < 4; ++v) {
    mA[v] = -INFINITY; lA[v] = 0.f;
    mC[v] = -INFINITY; lC[v] = 0.f;
  }

  bf16_t* PwA = Ps + wave * 1024;          // wave-private 16x64 (swizzled)
  bf16_t* PwC = Ps + 4096 + wave * 1024;

  // softmax in exp2 domain: p = 2^(s*scale*log2e - m)
  const float c1 = 0.08838834764831845f * 1.4426950408889634f;

  const int ntA = maskflag ? qa + 1 : (S_ / 64);
  const int ntC = maskflag ? qc + 1 : (S_ / 64);   // ntC <= ntA always

  auto softmax_chain = [&](f32x4 (&s)[4], float (&mrow)[4], float (&lrow)[4],
                           f32x4 (&acc)[8], bf16_t* Pw, bool masked)
      __attribute__((always_inline)) {
#pragma unroll
    for (int v = 0; v < 4; ++v) {
      float x[4];
#pragma unroll
      for (int nt = 0; nt < 4; ++nt) {
        float y = s[nt][v] * c1;
        if (masked) {
          int kg = nt * 16 + l16;
          int qg = wave * 16 + quad * 4 + v;
          if (kg > qg) y = -INFINITY;
        }
        x[nt] = y;
      }
      float r = fmaxf(fmaxf(x[0], x[1]), fmaxf(x[2], x[3]));
      r = rowmax16(r);
      float m = mrow[v];
      if (r > m + 8.f) {               // defer-max: rescale only on real growth
        float alpha = __builtin_amdgcn_exp2f(m - r);
        lrow[v] *= alpha;
#pragma unroll
        for (int dt = 0; dt < 8; ++dt) acc[dt][v] *= alpha;
        mrow[v] = r;
        m = r;
      }
      float rs = 0.f;
      int prow = quad * 4 + v;
#pragma unroll
      for (int nt = 0; nt < 4; ++nt) {
        float p = __builtin_amdgcn_exp2f(x[nt] - m);
        rs += p;
        Pw[prow * 64 + ((nt * 16 + l16) ^ ((prow & 7) << 3))] = (bf16_t)p;
      }
      lrow[v] += rowsum16(rs);
    }
  };

  auto body = [&](auto DOC, int cur, bool maskedA, bool maskedC)
      __attribute__((always_inline)) {
    constexpr bool doC = decltype(DOC)::v;
    const bf16_t* KsB = Ks + cur * 8192;
    const bf16_t* VsB = Vs + cur * 8192;

    // S = Q K^T for both chains; kf read once, feeds both MFMAs.
    f32x4 sA[4], sC[4];
#pragma unroll
    for (int nt = 0; nt < 4; ++nt) {
      sA[nt] = (f32x4){0.f, 0.f, 0.f, 0.f};
      sC[nt] = (f32x4){0.f, 0.f, 0.f, 0.f};
    }
    __builtin_amdgcn_s_setprio(1);
#pragma unroll
    for (int kk = 0; kk < 4; ++kk) {
#pragma unroll
      for (int nt = 0; nt < 4; ++nt) {
        bf16x8 kf = *(const bf16x8*)(KsB + (nt * 16 + l16) * 128 +
                                     ((kk * 32 + quad * 8) ^ ((l16 & 7) << 3)));
        sA[nt] = mfma16(qfA[kk], kf, sA[nt]);
        if constexpr (doC) sC[nt] = mfma16(qfC[kk], kf, sC[nt]);
      }
    }
    __builtin_amdgcn_s_setprio(0);

    softmax_chain(sA, mA, lA, accA, PwA, maskedA);
    if constexpr (doC) softmax_chain(sC, mC, lC, accC, PwC, maskedC);

    // O += P V for both chains; vf read once.
    __builtin_amdgcn_s_setprio(1);
#pragma unroll
    for (int kk = 0; kk < 2; ++kk) {
      bf16x8 pfA = *(const bf16x8*)(PwA + l16 * 64 +
                                    ((kk * 32 + quad * 8) ^ ((l16 & 7) << 3)));
      bf16x8 pfC = {};
      if constexpr (doC)
        pfC = *(const bf16x8*)(PwC + l16 * 64 +
                               ((kk * 32 + quad * 8) ^ ((l16 & 7) << 3)));
#pragma unroll
      for (int dt = 0; dt < 8; ++dt) {
        bf16x8 vf = *(const bf16x8*)(VsB + (dt * 16 + l16) * 64 +
                                     ((kk * 32 + quad * 8) ^ ((l16 & 7) << 3)));
        accA[dt] = mfma16(pfA, vf, accA[dt]);
        if constexpr (doC) accC[dt] = mfma16(pfC, vf, accC[dt]);
      }
    }
    __builtin_amdgcn_s_setprio(0);
  };

  __syncthreads();                       // drains prologue async copies

  for (int t = 0; t < ntA; ++t) {
    const int cur = t & 1;
    if (t + 1 < ntA) stage_kv(t + 1, cur ^ 1);     // prefetch next tile
    const bool mAf = maskflag && (t == qa);
    if (t < ntC)
      body(ChainOn{},  cur, mAf, maskflag && (t == qc));
    else
      body(ChainOff{}, cur, mAf, false);
    __syncthreads();   // reads of buf done + prefetch into buf^1 drained
  }

  // epilogue: O[q][d] = acc * (1/l)
  auto epilogue = [&](f32x4 (&acc)[8], float (&lrow)[4], size_t qbase)
      __attribute__((always_inline)) {
    float rl[4];
#pragma unroll
    for (int v = 0; v < 4; ++v) rl[v] = __builtin_amdgcn_rcpf(lrow[v]);
#pragma unroll
    for (int dt = 0; dt < 8; ++dt)
#pragma unroll
      for (int v = 0; v < 4; ++v) {
        int qr = wave * 16 + quad * 4 + v;
        O[qbase + (size_t)qr * DM_ + dt * 16 + l16] = (bf16_t)(acc[dt][v] * rl[v]);
      }
  };
  epilogue(accA, lA, qbaseA);
  epilogue(accC, lC, qbaseC);
}

// ---------------------------------------------------------------------------
extern "C" void kernel_launch(void* const* d_in, const int* in_sizes, int n_in,
                              void* d_out, int out_size, void* d_ws, size_t ws_size,
                              hipStream_t stream) {
  const float* x  = (const float*)d_in[0];
  const float* Wq = (const float*)d_in[1];
  const float* Wk = (const float*)d_in[2];
  const float* Wv = (const float*)d_in[3];
  const float* Wo = (const float*)d_in[4];
  const int* use_mask = (const int*)d_in[5];
  float* out = (float*)d_out;

  const size_t TSZ = (size_t)BS_ * DM_;   // 16,777,216 elems (32 MiB bf16)
  const size_t WSZ = (size_t)DM_ * DM_;   //  4,194,304 elems ( 8 MiB bf16)
  bf16_t* Qb  = (bf16_t*)d_ws;            // R0
  bf16_t* Kb  = Qb + TSZ;                 // R1
  bf16_t* Vt  = Kb + TSZ;                 // R2: Vt, then Wo_bf16 after attention
  bf16_t* xb  = Vt + TSZ;                 // R3: x_bf16, then Ob after projections
  bf16_t* Ob  = xb;
  bf16_t* Wob = Vt;
  // weight bf16 staging inside d_out (64 MiB fp32; fully overwritten at the end)
  bf16_t* wq = (bf16_t*)d_out;
  bf16_t* wk = wq + WSZ;
  bf16_t* wv = wk + WSZ;

  cvt_bf16<<<(int)(TSZ / 8 / 256), 256, 0, stream>>>(x,  xb, (int)(TSZ / 8));
  cvt_bf16<<<(int)(WSZ / 8 / 256), 256, 0, stream>>>(Wq, wq, (int)(WSZ / 8));
  cvt_bf16<<<(int)(WSZ / 8 / 256), 256, 0, stream>>>(Wk, wk, (int)(WSZ / 8));
  cvt_bf16<<<(int)(WSZ / 8 / 256), 256, 0, stream>>>(Wv, wv, (int)(WSZ / 8));

  dim3 gGemm(BS_ / 128, DM_ / 128);  // (64, 16)
  gemm_bt<bf16_t, false><<<gGemm, 256, 0, stream>>>(xb, wq, Qb, BS_, DM_, DM_);
  gemm_bt<bf16_t, false><<<gGemm, 256, 0, stream>>>(xb, wk, Kb, BS_, DM_, DM_);
  gemm_bt<bf16_t, true ><<<gGemm, 256, 0, stream>>>(xb, wv, Vt, BS_, DM_, DM_);

  dim3 gA(16, 64);                   // 1024 balanced dual-q blocks
  attn_kernel<<<gA, 256, 0, stream>>>(Qb, Kb, Vt, Ob, use_mask);

  cvt_bf16<<<(int)(WSZ / 8 / 256), 256, 0, stream>>>(Wo, Wob, (int)(WSZ / 8));
  gemm_bt<float, false><<<gGemm, 256, 0, stream>>>(Ob, Wob, out, BS_, DM_, DM_);
}